// Round 5
// baseline (330.106 us; speedup 1.0000x reference)
//
#include <hip/hip_runtime.h>
#include <hip/hip_bf16.h>

#define NGAUSS   50
#define HID      512
#define EMBD     256
#define NPID     10000         // 100*100 pair types
#define EBLK     64            // edges per block
#define GPAD     72            // u16 stride for g rows (144B)
#define PPAD     520           // u16 stride for h rows (1040B)
#define EPAD     264           // u16 stride for emb stage rows in P-GEMM (528B)

typedef __attribute__((ext_vector_type(8))) short   bfrag;   // 8 bf16
typedef __attribute__((ext_vector_type(4))) float   facc;    // 4 f32
typedef __attribute__((ext_vector_type(8))) unsigned short u16x8;
typedef __attribute__((ext_vector_type(4))) unsigned short u16x4;

// ---- workspace layout (bytes) ----
#define PBF_OFF    0                         // u16 [10000*512]      10,240,000
#define WC32_OFF   10240000                  // f32 [51*512] (row50 = combined bias) 104,448
#define W1BF_OFF   10344448                  // u16 [8*32*64*8]         262,144
#define WRBF_OFF   10606592                  // u16 [2*32*64*8]          65,536
#define WCBF_OFF   10672128                  // u16 [2*32*64*8]          65,536
#define W2F_OFF    10737664                  // u16 [16*64*8]            16,384

static __device__ __forceinline__ unsigned short f2bf(float f) {
    union { float f; unsigned u; } v; v.f = f;
    unsigned r = v.u + 0x7FFF + ((v.u >> 16) & 1);   // RTNE
    return (unsigned short)(r >> 16);
}
static __device__ __forceinline__ unsigned pack2bf(float a, float b) {
    __hip_bfloat162 t = __float22bfloat162_rn(make_float2(a, b));
    return *reinterpret_cast<unsigned*>(&t);
}
static __device__ __forceinline__ float bfu_lo(unsigned u) {
    union { unsigned u; float f; } v; v.u = u << 16; return v.f;
}
static __device__ __forceinline__ float bfu_hi(unsigned u) {
    union { unsigned u; float f; } v; v.u = u & 0xFFFF0000u; return v.f;
}

// ================= K0: Wcomb = W_rbf@W1top (fp32, row50 = b_rbf@W1top + b1), pack W1bot/Wrbf/W2 frags =================
// Fragment (kt,nt): elem j of lane l = W[k = kt*32 + (l>>4)*8 + j][col = nt*16 + (l&15)]
__global__ __launch_bounds__(256) void prep0(
    const float* __restrict__ W_rbf, const float* __restrict__ b_rbf,
    const float* __restrict__ W1, const float* __restrict__ b1,
    const float* __restrict__ W2, char* __restrict__ ws)
{
    const int b = blockIdx.x, tid = threadIdx.x;
    if (b < 102) {
        // ---- Wcomb fp32 rows 0..49, row 50 = b_rbf@W1top + b1 ----
        const int j = b >> 1, chalf = b & 1;
        const int c = chalf * 256 + tid;
        const float* row = (j < NGAUSS) ? &W_rbf[(size_t)j * HID] : b_rbf;
        float a0 = 0.f, a1 = 0.f, a2 = 0.f, a3 = 0.f;
        for (int k = 0; k < HID; k += 4) {
            a0 += row[k + 0] * W1[(size_t)(k + 0) * HID + c];
            a1 += row[k + 1] * W1[(size_t)(k + 1) * HID + c];
            a2 += row[k + 2] * W1[(size_t)(k + 2) * HID + c];
            a3 += row[k + 3] * W1[(size_t)(k + 3) * HID + c];
        }
        float acc = (a0 + a1) + (a2 + a3);
        ((float*)(ws + WC32_OFF))[j * HID + c] = (j < NGAUSS) ? acc : acc + b1[c];
    } else if (b < 166) {
        // ---- pack W1bot fragments: kt 0..7 over K=512..767 ----
        const int gid = (b - 102) * 256 + tid;          // [0, 16384)
        const int lane = gid & 63, tmp = gid >> 6, nt = tmp & 31, kt = tmp >> 5;
        const int c  = nt * 16 + (lane & 15);
        const int kb = HID + kt * 32 + ((lane >> 4) << 3);
        unsigned short* dst = (unsigned short*)(ws + W1BF_OFF);
        #pragma unroll
        for (int j = 0; j < 8; ++j)
            dst[(size_t)gid * 8 + j] = f2bf(W1[(size_t)(kb + j) * HID + c]);
    } else if (b < 182) {
        // ---- pack W_rbf fragments: kt 0..1 (K padded to 64; row 50 = b_rbf) ----
        const int gid = (b - 166) * 256 + tid;          // [0, 4096)
        const int lane = gid & 63, tmp = gid >> 6, nt = tmp & 31, kt = tmp >> 5;
        const int c  = nt * 16 + (lane & 15);
        const int kb = kt * 32 + ((lane >> 4) << 3);
        unsigned short* dst = (unsigned short*)(ws + WRBF_OFF);
        #pragma unroll
        for (int j = 0; j < 8; ++j) {
            int k = kb + j;
            unsigned short v = 0;
            if (k < NGAUSS)       v = f2bf(W_rbf[(size_t)k * HID + c]);
            else if (k == NGAUSS) v = f2bf(b_rbf[c]);
            dst[(size_t)gid * 8 + j] = v;
        }
    } else {
        // ---- pack W2^T fragments: kt 0..15, heads padded to 16 ----
        const int gid = (b - 182) * 256 + tid;          // [0, 1024)
        const int lane = gid & 63, kt = gid >> 6;
        const int col = lane & 15;
        const int kb  = kt * 32 + ((lane >> 4) << 3);
        unsigned short* dst = (unsigned short*)(ws + W2F_OFF);
        #pragma unroll
        for (int j = 0; j < 8; ++j)
            dst[(size_t)gid * 8 + j] = (col < 8) ? f2bf(W2[(size_t)(kb + j) * 8 + col]) : (unsigned short)0;
    }
}

// ================= K1: pack Wcomb frags (row50 = bias) + P = emb_table @ W1bot =================
__global__ __launch_bounds__(512) void prep1(
    const float* __restrict__ emb_table, char* __restrict__ ws)
{
    const int b = blockIdx.x, t = threadIdx.x;
    if (b < 8) {
        const int gid = b * 512 + t;                    // [0, 4096)
        const int lane = gid & 63, tmp = gid >> 6, nt = tmp & 31, kt = tmp >> 5;
        const int c  = nt * 16 + (lane & 15);
        const int kb = kt * 32 + ((lane >> 4) << 3);
        const float* wc = (const float*)(ws + WC32_OFF);
        unsigned short* dst = (unsigned short*)(ws + WCBF_OFF);
        #pragma unroll
        for (int j = 0; j < 8; ++j) {
            int k = kb + j;
            dst[(size_t)gid * 8 + j] = (k <= NGAUSS) ? f2bf(wc[k * HID + c]) : (unsigned short)0;
        }
        return;
    }
    __shared__ unsigned short s_e[64 * EPAD];
    const int pb = b - 8;                               // 0..156
    const int lane = t & 63, w = t >> 6;
    const int lq = lane >> 4, lr = lane & 15;
    {
        int row = t >> 3;
        int grow = pb * 64 + row; if (grow >= NPID) grow = NPID - 1;
        int c0 = (t & 7) * 32;
        #pragma unroll
        for (int ii = 0; ii < 8; ++ii) {
            const float4 v = *(const float4*)&emb_table[(size_t)grow * EMBD + c0 + ii * 4];
            u16x4 bv; bv[0] = f2bf(v.x); bv[1] = f2bf(v.y); bv[2] = f2bf(v.z); bv[3] = f2bf(v.w);
            *(u16x4*)&s_e[row * EPAD + c0 + ii * 4] = bv;
        }
    }
    __syncthreads();
    const int ntb = w * 4;
    const unsigned short* W1bf = (const unsigned short*)(ws + W1BF_OFF);
    unsigned short* Pbf = (unsigned short*)(ws + PBF_OFF);
    facc acc[4][4] = {};
    for (int kt = 0; kt < 8; ++kt) {
        bfrag a[4];
        #pragma unroll
        for (int mt = 0; mt < 4; ++mt)
            a[mt] = *(const bfrag*)&s_e[(mt * 16 + lr) * EPAD + kt * 32 + lq * 8];
        #pragma unroll
        for (int ntl = 0; ntl < 4; ++ntl) {
            bfrag bv = *(const bfrag*)&W1bf[((size_t)(kt * 32 + ntb + ntl) * 64 + lane) * 8];
            #pragma unroll
            for (int mt = 0; mt < 4; ++mt)
                acc[mt][ntl] = __builtin_amdgcn_mfma_f32_16x16x32_bf16(a[mt], bv, acc[mt][ntl], 0, 0, 0);
        }
    }
    #pragma unroll
    for (int ntl = 0; ntl < 4; ++ntl) {
        int col = (ntb + ntl) * 16 + lr;
        #pragma unroll
        for (int mt = 0; mt < 4; ++mt) {
            #pragma unroll
            for (int r = 0; r < 4; ++r) {
                int grow = pb * 64 + mt * 16 + lq * 4 + r;
                if (grow < NPID) Pbf[(size_t)grow * HID + col] = f2bf(acc[mt][ntl][r]);
            }
        }
    }
}

// ================= main fused kernel: 512 threads, 8 waves; TRANSPOSED GEMMs =================
__global__ __launch_bounds__(512, 4) void pair_embed_mfma(
    const int* __restrict__ anum,
    const int* __restrict__ row_index,
    const int* __restrict__ col_index,
    const float* __restrict__ dist,
    const float* __restrict__ b2,
    const char* __restrict__ ws,
    float* __restrict__ out,
    int n)
{
    extern __shared__ char smem[];
    unsigned short* s_buf = (unsigned short*)smem;                    // [64 edges][PPAD]: h rows
    unsigned short* s_g   = (unsigned short*)(smem + 64 * PPAD * 2);  // [64 edges][GPAD]
    float*          s_scr = (float*)(smem + 64 * PPAD * 2 + 64 * GPAD * 2);   // 4 KB phase-4 partials
    float*          s_d   = (float*)(smem + 64 * PPAD * 2 + 64 * GPAD * 2 + 4096);
    int*            s_pid = (int*)(smem + 64 * PPAD * 2 + 64 * GPAD * 2 + 4096 + 256);

    const unsigned short* Pbf   = (const unsigned short*)(ws + PBF_OFF);
    const unsigned short* Wrbff = (const unsigned short*)(ws + WRBF_OFF);
    const unsigned short* Wcbf  = (const unsigned short*)(ws + WCBF_OFF);
    const unsigned short* W2f   = (const unsigned short*)(ws + W2F_OFF);

    const int t = threadIdx.x, lane = t & 63, w = t >> 6;
    const int e0 = blockIdx.x * EBLK;
    const int lq = lane >> 4, lr = lane & 15;

    // ---- phase 0: metadata ----
    if (t < EBLK) {
        int e = e0 + t; if (e >= n) e = n - 1;
        s_d[t] = dist[e];
        s_pid[t] = anum[row_index[e]] + 100 * anum[col_index[e]];
    }
    __syncthreads();

    // ---- phase 1: gaussians -> s_g (K padded to 64; slot 50 = 1.0 for bias row) ----
    {
        const float sp = 12.0f / 49.0f;
        const float coeff = -0.5f / (sp * sp);
        int e = t >> 3, j0 = (t & 7) * 8;
        float d = s_d[e];
        float gv[8];
        #pragma unroll
        for (int j = 0; j < 8; ++j) {
            int jj = j0 + j;
            float v = d - (float)jj * sp;
            gv[j] = (jj < NGAUSS) ? __expf(coeff * v * v) : (jj == NGAUSS ? 1.0f : 0.0f);
        }
        uint4 pk;
        pk.x = pack2bf(gv[0], gv[1]); pk.y = pack2bf(gv[2], gv[3]);
        pk.z = pack2bf(gv[4], gv[5]); pk.w = pack2bf(gv[6], gv[7]);
        *(uint4*)&s_g[e * GPAD + j0] = pk;
    }

    // ---- A-operand fragments (wave's 64 hidden cols): loop-invariant ----
    const int mtb = w * 4;
    bfrag aR[2][4], aC[2][4];
    #pragma unroll
    for (int kt = 0; kt < 2; ++kt)
        #pragma unroll
        for (int m = 0; m < 4; ++m) {
            aR[kt][m] = *(const bfrag*)&Wrbff[((size_t)(kt * 32 + mtb + m) * 64 + lane) * 8];
            aC[kt][m] = *(const bfrag*)&Wcbf [((size_t)(kt * 32 + mtb + m) * 64 + lane) * 8];
        }
    __syncthreads();

    // ---- phase 2+3: per 16-edge tile: twin MFMAs + vectorized epilogue ----
    for (int nt4 = 0; nt4 < 4; ++nt4) {
        const int e = nt4 * 16 + lr;
        const int pid = s_pid[e];
        uint2 pv[4];
        {
            const unsigned short* prow = Pbf + (size_t)pid * HID + w * 64 + lq * 4;
            #pragma unroll
            for (int m = 0; m < 4; ++m) pv[m] = *(const uint2*)&prow[m * 16];
        }
        bfrag g0 = *(const bfrag*)&s_g[e * GPAD + lq * 8];
        bfrag g1 = *(const bfrag*)&s_g[e * GPAD + 32 + lq * 8];
        facc racc[4] = {}, cacc[4] = {};
        #pragma unroll
        for (int m = 0; m < 4; ++m) {
            racc[m] = __builtin_amdgcn_mfma_f32_16x16x32_bf16(aR[0][m], g0, racc[m], 0, 0, 0);
            cacc[m] = __builtin_amdgcn_mfma_f32_16x16x32_bf16(aC[0][m], g0, cacc[m], 0, 0, 0);
        }
        #pragma unroll
        for (int m = 0; m < 4; ++m) {
            racc[m] = __builtin_amdgcn_mfma_f32_16x16x32_bf16(aR[1][m], g1, racc[m], 0, 0, 0);
            cacc[m] = __builtin_amdgcn_mfma_f32_16x16x32_bf16(aC[1][m], g1, cacc[m], 0, 0, 0);
        }
        // epilogue: pre = cacc + P ; h = silu(pre) * rbf ; vector write
        #pragma unroll
        for (int m = 0; m < 4; ++m) {
            float p0 = bfu_lo(pv[m].x), p1 = bfu_hi(pv[m].x);
            float p2 = bfu_lo(pv[m].y), p3 = bfu_hi(pv[m].y);
            float pr0 = cacc[m][0] + p0, pr1 = cacc[m][1] + p1;
            float pr2 = cacc[m][2] + p2, pr3 = cacc[m][3] + p3;
            float h0 = pr0 * __builtin_amdgcn_rcpf(1.0f + __expf(-pr0)) * racc[m][0];
            float h1 = pr1 * __builtin_amdgcn_rcpf(1.0f + __expf(-pr1)) * racc[m][1];
            float h2 = pr2 * __builtin_amdgcn_rcpf(1.0f + __expf(-pr2)) * racc[m][2];
            float h3 = pr3 * __builtin_amdgcn_rcpf(1.0f + __expf(-pr3)) * racc[m][3];
            uint2 hw;
            hw.x = pack2bf(h0, h1);
            hw.y = pack2bf(h2, h3);
            *(uint2*)&s_buf[e * PPAD + w * 64 + m * 16 + lq * 4] = hw;
        }
    }
    __syncthreads();

    // ---- phase 4: out[head][e] = (W2^T @ h^T) + b2; 2-way K-split across wave pairs ----
    {
        const int nt4 = w & 3;          // 16-edge tile
        const int ks  = w >> 2;         // k-half (8 kt each)
        facc a4 = {};
        #pragma unroll
        for (int kq = 0; kq < 8; ++kq) {
            int kt = ks * 8 + kq;
            bfrag hfrag = *(const bfrag*)&s_buf[(nt4 * 16 + lr) * PPAD + kt * 32 + lq * 8];
            bfrag wfrag = *(const bfrag*)&W2f[((size_t)kt * 64 + lane) * 8];
            a4 = __builtin_amdgcn_mfma_f32_16x16x32_bf16(wfrag, hfrag, a4, 0, 0, 0);
        }
        if (ks == 1) *(facc*)&s_scr[(nt4 * 64 + lane) * 4] = a4;
        __syncthreads();
        if (ks == 0 && lq < 2) {
            facc oth = *(const facc*)&s_scr[(nt4 * 64 + lane) * 4];
            const int e = e0 + nt4 * 16 + lr;
            if (e < n) {
                #pragma unroll
                for (int r = 0; r < 4; ++r) {
                    int head = lq * 4 + r;
                    out[(size_t)head * n + e] = a4[r] + oth[r] + b2[head];
                }
            }
        }
    }
}

extern "C" void kernel_launch(void* const* d_in, const int* in_sizes, int n_in,
                              void* d_out, int out_size, void* d_ws, size_t ws_size,
                              hipStream_t stream) {
    const int*   anum      = (const int*)d_in[0];
    const int*   row_index = (const int*)d_in[1];
    const int*   col_index = (const int*)d_in[2];
    const float* dist      = (const float*)d_in[3];
    const float* W_rbf     = (const float*)d_in[4];
    const float* b_rbf     = (const float*)d_in[5];
    const float* emb_table = (const float*)d_in[6];
    const float* W1        = (const float*)d_in[7];
    const float* b1        = (const float*)d_in[8];
    const float* W2        = (const float*)d_in[9];
    const float* b2        = (const float*)d_in[10];
    float* out = (float*)d_out;
    char* ws = (char*)d_ws;

    const int n_edges = in_sizes[3];

    prep0<<<186, 256, 0, stream>>>(W_rbf, b_rbf, W1, b1, W2, ws);
    prep1<<<8 + 157, 512, 0, stream>>>(emb_table, ws);

    const int grid = (n_edges + EBLK - 1) / EBLK;
    const size_t lds_bytes = 64 * PPAD * 2 + 64 * GPAD * 2 + 4096 + 256 + 256;  // 80384
    pair_embed_mfma<<<grid, 512, lds_bytes, stream>>>(
        anum, row_index, col_index, dist, b2, ws, out, n_edges);
}

// Round 6
// 182.026 us; speedup vs baseline: 1.8135x; 1.8135x over previous
//
#include <hip/hip_runtime.h>
#include <hip/hip_bf16.h>

#define NGAUSS   50
#define HID      512
#define EMBD     256
#define NPID     10000         // 100*100 pair types
#define EBLK     64            // edges per block
#define GPAD     72            // u16 stride for g rows (144B)
#define PPAD     520           // u16 stride for h rows (1040B)
#define EPAD     264           // u16 stride for emb stage rows in P-GEMM (528B)

typedef __attribute__((ext_vector_type(8))) short   bfrag;   // 8 bf16
typedef __attribute__((ext_vector_type(4))) float   facc;    // 4 f32
typedef __attribute__((ext_vector_type(8))) unsigned short u16x8;
typedef __attribute__((ext_vector_type(4))) unsigned short u16x4;

// ---- workspace layout (bytes) ----
#define PBF_OFF    0                         // u16 [10000*512]      10,240,000 (PERMUTED rows)
#define WC32_OFF   10240000                  // f32 [51*512] (row50 = combined bias) 104,448
#define W1BF_OFF   10344448                  // u16 [8*32*64*8]         262,144
#define WRBF_OFF   10606592                  // u16 [2*32*64*8]          65,536
#define WCBF_OFF   10672128                  // u16 [2*32*64*8]          65,536
#define W2F_OFF    10737664                  // u16 [16*64*8]            16,384

static __device__ __forceinline__ unsigned short f2bf(float f) {
    union { float f; unsigned u; } v; v.f = f;
    unsigned r = v.u + 0x7FFF + ((v.u >> 16) & 1);   // RTNE
    return (unsigned short)(r >> 16);
}
static __device__ __forceinline__ unsigned pack2bf(float a, float b) {
    __hip_bfloat162 t = __float22bfloat162_rn(make_float2(a, b));
    return *reinterpret_cast<unsigned*>(&t);
}
static __device__ __forceinline__ float bfu_lo(unsigned u) {
    union { unsigned u; float f; } v; v.u = u << 16; return v.f;
}
static __device__ __forceinline__ float bfu_hi(unsigned u) {
    union { unsigned u; float f; } v; v.u = u & 0xFFFF0000u; return v.f;
}

// ================= K0: Wcomb = W_rbf@W1top (fp32, row50 = b_rbf@W1top + b1), pack W1bot/Wrbf/W2 frags =================
// Fragment (kt,nt): elem j of lane l = W[k = kt*32 + (l>>4)*8 + j][col = nt*16 + (l&15)]
__global__ __launch_bounds__(256) void prep0(
    const float* __restrict__ W_rbf, const float* __restrict__ b_rbf,
    const float* __restrict__ W1, const float* __restrict__ b1,
    const float* __restrict__ W2, char* __restrict__ ws)
{
    const int b = blockIdx.x, tid = threadIdx.x;
    if (b < 102) {
        // ---- Wcomb fp32 rows 0..49, row 50 = b_rbf@W1top + b1 ----
        const int j = b >> 1, chalf = b & 1;
        const int c = chalf * 256 + tid;
        const float* row = (j < NGAUSS) ? &W_rbf[(size_t)j * HID] : b_rbf;
        float a0 = 0.f, a1 = 0.f, a2 = 0.f, a3 = 0.f;
        for (int k = 0; k < HID; k += 4) {
            a0 += row[k + 0] * W1[(size_t)(k + 0) * HID + c];
            a1 += row[k + 1] * W1[(size_t)(k + 1) * HID + c];
            a2 += row[k + 2] * W1[(size_t)(k + 2) * HID + c];
            a3 += row[k + 3] * W1[(size_t)(k + 3) * HID + c];
        }
        float acc = (a0 + a1) + (a2 + a3);
        ((float*)(ws + WC32_OFF))[j * HID + c] = (j < NGAUSS) ? acc : acc + b1[c];
    } else if (b < 166) {
        // ---- pack W1bot fragments: kt 0..7 over K=512..767 ----
        const int gid = (b - 102) * 256 + tid;          // [0, 16384)
        const int lane = gid & 63, tmp = gid >> 6, nt = tmp & 31, kt = tmp >> 5;
        const int c  = nt * 16 + (lane & 15);
        const int kb = HID + kt * 32 + ((lane >> 4) << 3);
        unsigned short* dst = (unsigned short*)(ws + W1BF_OFF);
        #pragma unroll
        for (int j = 0; j < 8; ++j)
            dst[(size_t)gid * 8 + j] = f2bf(W1[(size_t)(kb + j) * HID + c]);
    } else if (b < 182) {
        // ---- pack W_rbf fragments: kt 0..1 (K padded to 64; row 50 = b_rbf) ----
        const int gid = (b - 166) * 256 + tid;          // [0, 4096)
        const int lane = gid & 63, tmp = gid >> 6, nt = tmp & 31, kt = tmp >> 5;
        const int c  = nt * 16 + (lane & 15);
        const int kb = kt * 32 + ((lane >> 4) << 3);
        unsigned short* dst = (unsigned short*)(ws + WRBF_OFF);
        #pragma unroll
        for (int j = 0; j < 8; ++j) {
            int k = kb + j;
            unsigned short v = 0;
            if (k < NGAUSS)       v = f2bf(W_rbf[(size_t)k * HID + c]);
            else if (k == NGAUSS) v = f2bf(b_rbf[c]);
            dst[(size_t)gid * 8 + j] = v;
        }
    } else {
        // ---- pack W2^T fragments: kt 0..15, heads padded to 16 ----
        const int gid = (b - 182) * 256 + tid;          // [0, 1024)
        const int lane = gid & 63, kt = gid >> 6;
        const int col = lane & 15;
        const int kb  = kt * 32 + ((lane >> 4) << 3);
        unsigned short* dst = (unsigned short*)(ws + W2F_OFF);
        #pragma unroll
        for (int j = 0; j < 8; ++j)
            dst[(size_t)gid * 8 + j] = (col < 8) ? f2bf(W2[(size_t)(kb + j) * 8 + col]) : (unsigned short)0;
    }
}

// ================= K1: pack Wcomb frags (row50 = bias) + P = emb_table @ W1bot =================
// P rows stored PERMUTED: element for hidden col c goes to offset W*64 + L*16 + M*4 + J
// where c = W*64 + M*16 + L*4 + J  -> each main-kernel thread's 16 values are 32B contiguous.
__global__ __launch_bounds__(512) void prep1(
    const float* __restrict__ emb_table, char* __restrict__ ws)
{
    const int b = blockIdx.x, t = threadIdx.x;
    if (b < 8) {
        const int gid = b * 512 + t;                    // [0, 4096)
        const int lane = gid & 63, tmp = gid >> 6, nt = tmp & 31, kt = tmp >> 5;
        const int c  = nt * 16 + (lane & 15);
        const int kb = kt * 32 + ((lane >> 4) << 3);
        const float* wc = (const float*)(ws + WC32_OFF);
        unsigned short* dst = (unsigned short*)(ws + WCBF_OFF);
        #pragma unroll
        for (int j = 0; j < 8; ++j) {
            int k = kb + j;
            dst[(size_t)gid * 8 + j] = (k <= NGAUSS) ? f2bf(wc[k * HID + c]) : (unsigned short)0;
        }
        return;
    }
    __shared__ unsigned short s_e[64 * EPAD];
    const int pb = b - 8;                               // 0..156
    const int lane = t & 63, w = t >> 6;
    const int lq = lane >> 4, lr = lane & 15;
    {
        int row = t >> 3;
        int grow = pb * 64 + row; if (grow >= NPID) grow = NPID - 1;
        int c0 = (t & 7) * 32;
        #pragma unroll
        for (int ii = 0; ii < 8; ++ii) {
            const float4 v = *(const float4*)&emb_table[(size_t)grow * EMBD + c0 + ii * 4];
            u16x4 bv; bv[0] = f2bf(v.x); bv[1] = f2bf(v.y); bv[2] = f2bf(v.z); bv[3] = f2bf(v.w);
            *(u16x4*)&s_e[row * EPAD + c0 + ii * 4] = bv;
        }
    }
    __syncthreads();
    const int ntb = w * 4;
    const unsigned short* W1bf = (const unsigned short*)(ws + W1BF_OFF);
    unsigned short* Pbf = (unsigned short*)(ws + PBF_OFF);
    facc acc[4][4] = {};
    for (int kt = 0; kt < 8; ++kt) {
        bfrag a[4];
        #pragma unroll
        for (int mt = 0; mt < 4; ++mt)
            a[mt] = *(const bfrag*)&s_e[(mt * 16 + lr) * EPAD + kt * 32 + lq * 8];
        #pragma unroll
        for (int ntl = 0; ntl < 4; ++ntl) {
            bfrag bv = *(const bfrag*)&W1bf[((size_t)(kt * 32 + ntb + ntl) * 64 + lane) * 8];
            #pragma unroll
            for (int mt = 0; mt < 4; ++mt)
                acc[mt][ntl] = __builtin_amdgcn_mfma_f32_16x16x32_bf16(a[mt], bv, acc[mt][ntl], 0, 0, 0);
        }
    }
    #pragma unroll
    for (int ntl = 0; ntl < 4; ++ntl) {
        const int col = (ntb + ntl) * 16 + lr;
        const int Wd = col >> 6, Md = (col >> 4) & 3, Ld = (col >> 2) & 3, Jd = col & 3;
        const int off = Wd * 64 + Ld * 16 + Md * 4 + Jd;   // permuted position
        #pragma unroll
        for (int mt = 0; mt < 4; ++mt) {
            #pragma unroll
            for (int r = 0; r < 4; ++r) {
                int grow = pb * 64 + mt * 16 + lq * 4 + r;
                if (grow < NPID) Pbf[(size_t)grow * HID + off] = f2bf(acc[mt][ntl][r]);
            }
        }
    }
}

// ================= main fused kernel: 512 threads, 8 waves; TRANSPOSED GEMMs =================
__global__ __launch_bounds__(512, 4) void pair_embed_mfma(
    const int* __restrict__ anum,
    const int* __restrict__ row_index,
    const int* __restrict__ col_index,
    const float* __restrict__ dist,
    const float* __restrict__ b2,
    const char* __restrict__ ws,
    float* __restrict__ out,
    int n)
{
    extern __shared__ char smem[];
    unsigned short* s_buf = (unsigned short*)smem;                    // [64 edges][PPAD]: h rows
    unsigned short* s_g   = (unsigned short*)(smem + 64 * PPAD * 2);  // [64 edges][GPAD]
    float*          s_scr = (float*)(smem + 64 * PPAD * 2 + 64 * GPAD * 2);   // 4 KB phase-4 partials
    float*          s_d   = (float*)(smem + 64 * PPAD * 2 + 64 * GPAD * 2 + 4096);
    int*            s_pid = (int*)(smem + 64 * PPAD * 2 + 64 * GPAD * 2 + 4096 + 256);

    const unsigned short* Pbf   = (const unsigned short*)(ws + PBF_OFF);
    const unsigned short* Wrbff = (const unsigned short*)(ws + WRBF_OFF);
    const unsigned short* Wcbf  = (const unsigned short*)(ws + WCBF_OFF);
    const unsigned short* W2f   = (const unsigned short*)(ws + W2F_OFF);

    const int t = threadIdx.x, lane = t & 63, w = t >> 6;
    const int e0 = blockIdx.x * EBLK;
    const int lq = lane >> 4, lr = lane & 15;

    // ---- phase 0: metadata ----
    if (t < EBLK) {
        int e = e0 + t; if (e >= n) e = n - 1;
        s_d[t] = dist[e];
        s_pid[t] = anum[row_index[e]] + 100 * anum[col_index[e]];
    }
    __syncthreads();

    // ---- issue tile-0 P loads EARLY (hide latency under gaussian + A-frag setup) ----
    const size_t pbase_off = (size_t)(w * 64 + lq * 16);
    uint4 q0, q1;
    {
        const unsigned short* prow = Pbf + (size_t)s_pid[lr] * HID + pbase_off;
        q0 = *(const uint4*)&prow[0];
        q1 = *(const uint4*)&prow[8];
    }

    // ---- phase 1: gaussians -> s_g (K padded to 64; slot 50 = 1.0 for bias row) ----
    {
        const float sp = 12.0f / 49.0f;
        const float coeff = -0.5f / (sp * sp);
        int e = t >> 3, j0 = (t & 7) * 8;
        float d = s_d[e];
        float gv[8];
        #pragma unroll
        for (int j = 0; j < 8; ++j) {
            int jj = j0 + j;
            float v = d - (float)jj * sp;
            gv[j] = (jj < NGAUSS) ? __expf(coeff * v * v) : (jj == NGAUSS ? 1.0f : 0.0f);
        }
        uint4 pk;
        pk.x = pack2bf(gv[0], gv[1]); pk.y = pack2bf(gv[2], gv[3]);
        pk.z = pack2bf(gv[4], gv[5]); pk.w = pack2bf(gv[6], gv[7]);
        *(uint4*)&s_g[e * GPAD + j0] = pk;
    }

    // ---- A-operand fragments (wave's 64 hidden cols): loop-invariant ----
    const int mtb = w * 4;
    bfrag aR[2][4], aC[2][4];
    #pragma unroll
    for (int kt = 0; kt < 2; ++kt)
        #pragma unroll
        for (int m = 0; m < 4; ++m) {
            aR[kt][m] = *(const bfrag*)&Wrbff[((size_t)(kt * 32 + mtb + m) * 64 + lane) * 8];
            aC[kt][m] = *(const bfrag*)&Wcbf [((size_t)(kt * 32 + mtb + m) * 64 + lane) * 8];
        }
    __syncthreads();

    // ---- phase 2+3: per 16-edge tile: twin MFMAs + vectorized epilogue (P pipelined 1 ahead) ----
    for (int nt4 = 0; nt4 < 4; ++nt4) {
        const uint4 c0 = q0, c1 = q1;
        if (nt4 < 3) {
            const unsigned short* prow = Pbf + (size_t)s_pid[(nt4 + 1) * 16 + lr] * HID + pbase_off;
            q0 = *(const uint4*)&prow[0];
            q1 = *(const uint4*)&prow[8];
        }
        const int e = nt4 * 16 + lr;
        bfrag g0 = *(const bfrag*)&s_g[e * GPAD + lq * 8];
        bfrag g1 = *(const bfrag*)&s_g[e * GPAD + 32 + lq * 8];
        facc racc[4] = {}, cacc[4] = {};
        #pragma unroll
        for (int m = 0; m < 4; ++m) {
            racc[m] = __builtin_amdgcn_mfma_f32_16x16x32_bf16(aR[0][m], g0, racc[m], 0, 0, 0);
            cacc[m] = __builtin_amdgcn_mfma_f32_16x16x32_bf16(aC[0][m], g0, cacc[m], 0, 0, 0);
        }
        #pragma unroll
        for (int m = 0; m < 4; ++m) {
            racc[m] = __builtin_amdgcn_mfma_f32_16x16x32_bf16(aR[1][m], g1, racc[m], 0, 0, 0);
            cacc[m] = __builtin_amdgcn_mfma_f32_16x16x32_bf16(aC[1][m], g1, cacc[m], 0, 0, 0);
        }
        // epilogue: pre = cacc + P ; h = silu(pre) * rbf ; vector write
        const uint2 pv[4] = { make_uint2(c0.x, c0.y), make_uint2(c0.z, c0.w),
                              make_uint2(c1.x, c1.y), make_uint2(c1.z, c1.w) };
        #pragma unroll
        for (int m = 0; m < 4; ++m) {
            float p0 = bfu_lo(pv[m].x), p1 = bfu_hi(pv[m].x);
            float p2 = bfu_lo(pv[m].y), p3 = bfu_hi(pv[m].y);
            float pr0 = cacc[m][0] + p0, pr1 = cacc[m][1] + p1;
            float pr2 = cacc[m][2] + p2, pr3 = cacc[m][3] + p3;
            float h0 = pr0 * __builtin_amdgcn_rcpf(1.0f + __expf(-pr0)) * racc[m][0];
            float h1 = pr1 * __builtin_amdgcn_rcpf(1.0f + __expf(-pr1)) * racc[m][1];
            float h2 = pr2 * __builtin_amdgcn_rcpf(1.0f + __expf(-pr2)) * racc[m][2];
            float h3 = pr3 * __builtin_amdgcn_rcpf(1.0f + __expf(-pr3)) * racc[m][3];
            uint2 hw;
            hw.x = pack2bf(h0, h1);
            hw.y = pack2bf(h2, h3);
            *(uint2*)&s_buf[e * PPAD + w * 64 + m * 16 + lq * 4] = hw;
        }
    }
    __syncthreads();

    // ---- phase 4: out[head][e] = (W2^T @ h^T) + b2; 2-way K-split across wave pairs ----
    {
        const int nt4 = w & 3;          // 16-edge tile
        const int ks  = w >> 2;         // k-half (8 kt each)
        facc a4 = {};
        #pragma unroll
        for (int kq = 0; kq < 8; ++kq) {
            int kt = ks * 8 + kq;
            bfrag hfrag = *(const bfrag*)&s_buf[(nt4 * 16 + lr) * PPAD + kt * 32 + lq * 8];
            bfrag wfrag = *(const bfrag*)&W2f[((size_t)kt * 64 + lane) * 8];
            a4 = __builtin_amdgcn_mfma_f32_16x16x32_bf16(wfrag, hfrag, a4, 0, 0, 0);
        }
        if (ks == 1) *(facc*)&s_scr[(nt4 * 64 + lane) * 4] = a4;
        __syncthreads();
        if (ks == 0 && lq < 2) {
            facc oth = *(const facc*)&s_scr[(nt4 * 64 + lane) * 4];
            const int e = e0 + nt4 * 16 + lr;
            if (e < n) {
                #pragma unroll
                for (int r = 0; r < 4; ++r) {
                    int head = lq * 4 + r;
                    out[(size_t)head * n + e] = a4[r] + oth[r] + b2[head];
                }
            }
        }
    }
}

extern "C" void kernel_launch(void* const* d_in, const int* in_sizes, int n_in,
                              void* d_out, int out_size, void* d_ws, size_t ws_size,
                              hipStream_t stream) {
    const int*   anum      = (const int*)d_in[0];
    const int*   row_index = (const int*)d_in[1];
    const int*   col_index = (const int*)d_in[2];
    const float* dist      = (const float*)d_in[3];
    const float* W_rbf     = (const float*)d_in[4];
    const float* b_rbf     = (const float*)d_in[5];
    const float* emb_table = (const float*)d_in[6];
    const float* W1        = (const float*)d_in[7];
    const float* b1        = (const float*)d_in[8];
    const float* W2        = (const float*)d_in[9];
    const float* b2        = (const float*)d_in[10];
    float* out = (float*)d_out;
    char* ws = (char*)d_ws;

    const int n_edges = in_sizes[3];

    prep0<<<186, 256, 0, stream>>>(W_rbf, b_rbf, W1, b1, W2, ws);
    prep1<<<8 + 157, 512, 0, stream>>>(emb_table, ws);

    const int grid = (n_edges + EBLK - 1) / EBLK;
    const size_t lds_bytes = 64 * PPAD * 2 + 64 * GPAD * 2 + 4096 + 256 + 256;  // 80384
    pair_embed_mfma<<<grid, 512, lds_bytes, stream>>>(
        anum, row_index, col_index, dist, b2, ws, out, n_edges);
}